// Round 4
// baseline (29346.249 us; speedup 1.0000x reference)
//
#include <hip/hip_runtime.h>
#include <cstdint>

// Problem dims
#define TE    512
#define SD    128

typedef unsigned short u16;
typedef u16 u16x4 __attribute__((ext_vector_type(4)));
typedef u16 u16x8 __attribute__((ext_vector_type(8)));

// State region offsets (floats), relative to st pointer (st = d_ws + 67,108,864 B)
#define QO    0          // [32][1024]
#define SCO   32768      // [32][512]
#define BARO  49152      // grid-barrier arrival counter
#define FLGO  49216      // grid-barrier release flag (separate cache line)
#define CTXO  81920      // [32][1024]
#define YO    114688     // [32][128]
#define H0O   118784     // [2][32][512]
#define C0O   151552
#define H1O   184320
#define C1O   217088

__device__ __forceinline__ float b2f(u16 v) { return __uint_as_float(((unsigned)v) << 16); }
__device__ __forceinline__ u16 f2b(float f) {
  unsigned u = __float_as_uint(f);
  return (u16)((u + 0x7FFFu + ((u >> 16) & 1u)) >> 16);
}
__device__ __forceinline__ float tanh_f(float x) {
  float xc = fminf(12.f, fmaxf(-12.f, x));
  float e  = __expf(2.f * xc);
  return __fdividef(e - 1.f, e + 1.f);
}
__device__ __forceinline__ float sigm(float x) {
  float xc = fminf(30.f, fmaxf(-30.f, x));
  return __fdividef(1.f, 1.f + __expf(-xc));
}

// ---- device-coherent (sc1) accessors: bypass non-coherent per-XCD L2 ----
__device__ __forceinline__ void ld_dev4x4(const float* p0, const float* p1,
                                          const float* p2, const float* p3,
                                          float4& r0, float4& r1, float4& r2, float4& r3) {
  asm volatile(
    "global_load_dwordx4 %0, %4, off sc1\n\t"
    "global_load_dwordx4 %1, %5, off sc1\n\t"
    "global_load_dwordx4 %2, %6, off sc1\n\t"
    "global_load_dwordx4 %3, %7, off sc1\n\t"
    "s_waitcnt vmcnt(0)"
    : "=&v"(r0), "=&v"(r1), "=&v"(r2), "=&v"(r3)
    : "v"(p0), "v"(p1), "v"(p2), "v"(p3)
    : "memory");
}
__device__ __forceinline__ float ld_dev1(const float* p) {
  float r;
  asm volatile("global_load_dword %0, %1, off sc1\n\ts_waitcnt vmcnt(0)"
               : "=&v"(r) : "v"(p) : "memory");
  return r;
}
__device__ __forceinline__ void st_dev1(float* p, float v) {
  asm volatile("global_store_dword %0, %1, off sc1" :: "v"(p), "v"(v) : "memory");
}
// issue-only sc1 float4 load (no wait); pair with vm_wait0()
__device__ __forceinline__ void ld4_issue(const float* p, float4& r) {
  asm volatile("global_load_dwordx4 %0, %1, off sc1" : "=&v"(r) : "v"(p));
}
__device__ __forceinline__ void vm_wait0() { asm volatile("s_waitcnt vmcnt(0)" ::: "memory"); }

// ---------------- NT GEMM: key=E@Wk^T, value=E@Wv^T (fp32 in, bf16 out) ----------------
__global__ __launch_bounds__(256)
void gemm_kv(const float* __restrict__ E, const float* __restrict__ Wk,
             const float* __restrict__ Wv, u16* __restrict__ key, u16* __restrict__ value) {
  const float* B = blockIdx.z ? Wv : Wk;
  u16* outp = blockIdx.z ? value : key;
  __shared__ float Asm[16][68], Bsm[16][68];
  const int tid = threadIdx.x;
  const int tm = blockIdx.x * 64, tn = blockIdx.y * 64;
  const int lr = tid >> 2, lc = (tid & 3) * 4;
  const int tx = tid & 15, ty = tid >> 4;
  float acc[4][4] = {};
  for (int k0 = 0; k0 < 1024; k0 += 16) {
    float4 av = *(const float4*)(&E[(long)(tm + lr) * 1024 + k0 + lc]);
    float4 bv = *(const float4*)(&B[(long)(tn + lr) * 1024 + k0 + lc]);
    Asm[lc][lr] = av.x; Asm[lc + 1][lr] = av.y; Asm[lc + 2][lr] = av.z; Asm[lc + 3][lr] = av.w;
    Bsm[lc][lr] = bv.x; Bsm[lc + 1][lr] = bv.y; Bsm[lc + 2][lr] = bv.z; Bsm[lc + 3][lr] = bv.w;
    __syncthreads();
#pragma unroll
    for (int kk = 0; kk < 16; ++kk) {
      float4 a4 = *(const float4*)(&Asm[kk][ty * 4]);
      float4 b4 = *(const float4*)(&Bsm[kk][tx * 4]);
      acc[0][0] += a4.x * b4.x; acc[0][1] += a4.x * b4.y; acc[0][2] += a4.x * b4.z; acc[0][3] += a4.x * b4.w;
      acc[1][0] += a4.y * b4.x; acc[1][1] += a4.y * b4.y; acc[1][2] += a4.y * b4.z; acc[1][3] += a4.y * b4.w;
      acc[2][0] += a4.z * b4.x; acc[2][1] += a4.z * b4.y; acc[2][2] += a4.z * b4.z; acc[2][3] += a4.z * b4.w;
      acc[3][0] += a4.w * b4.x; acc[3][1] += a4.w * b4.y; acc[3][2] += a4.w * b4.z; acc[3][3] += a4.w * b4.w;
    }
    __syncthreads();
  }
#pragma unroll
  for (int i = 0; i < 4; ++i)
#pragma unroll
    for (int j = 0; j < 4; ++j)
      outp[(long)(tm + ty * 4 + i) * 1024 + tn + tx * 4 + j] = f2b(acc[i][j]);
}

// ---------------- init: h/c -> parity-0 state, zero y, zero barrier ----------------
__global__ __launch_bounds__(256)
void init_state(const float* __restrict__ h0, const float* __restrict__ c0, float* __restrict__ st) {
  int i = blockIdx.x * 256 + threadIdx.x;   // 16384 threads
  st[H0O + i] = h0[i];
  st[H1O + i] = h0[16384 + i];
  st[C0O + i] = c0[i];
  st[C1O + i] = c0[16384 + i];
  if (i < 4096) st[YO + i] = 0.f;
  if (i == 0) { *(unsigned*)(st + BARO) = 0u; *(unsigned*)(st + FLGO) = 0u; }
}

// ---------------- q0 = h0_layer0 @ Wq^T ----------------
__global__ __launch_bounds__(256)
void qproj(const float* __restrict__ h0, const float* __restrict__ Wq, float* __restrict__ st) {
  __shared__ float hr[512];
  const int b = blockIdx.x >> 2, o = (blockIdx.x & 3) * 256 + threadIdx.x;
  for (int i = threadIdx.x; i < 512; i += 256) hr[i] = h0[b * 512 + i];
  __syncthreads();
  float acc = 0.f;
  for (int k = 0; k < 512; k += 4) {
    float4 wv = *(const float4*)(&Wq[(long)o * 512 + k]);
    acc += hr[k] * wv.x + hr[k + 1] * wv.y + hr[k + 2] * wv.z + hr[k + 3] * wv.w;
  }
  st[QO + b * 1024 + o] = acc;
}

// ---------------- fused persistent decode loop: 256 blocks x 1024 threads ----------------
// 16 waves/CU (occupancy 50%); sc1 state transport; flag barrier (no L2 flush).
__global__ __launch_bounds__(1024, 4)
void decode_loop(const u16* __restrict__ key, const u16* __restrict__ value,
                 const float* __restrict__ We,
                 const float* __restrict__ wih0, const float* __restrict__ whh0,
                 const float* __restrict__ bih0, const float* __restrict__ bhh0,
                 const float* __restrict__ wih1, const float* __restrict__ whh1,
                 const float* __restrict__ bih1, const float* __restrict__ bhh1,
                 const float* __restrict__ Wq,
                 const float* __restrict__ fcw, const float* __restrict__ fcb,
                 float* st, float* out) {
  __shared__ float smem[14000];   // max phase D: xs 4224 + wr 1584 + gp 8192
  const int tid = threadIdx.x, wv = tid >> 6, ln = tid & 63;
  const int bid = blockIdx.x;
  unsigned* bar  = (unsigned*)(st + BARO);
  unsigned* flag = (unsigned*)(st + FLGO);
  unsigned bt = 0;

#define GBAR() do {                                                                     \
    ++bt;                                                                               \
    asm volatile("s_waitcnt vmcnt(0)" ::: "memory");                                    \
    __syncthreads();                                                                    \
    if (tid == 0) {                                                                     \
      unsigned old = __hip_atomic_fetch_add(bar, 1u, __ATOMIC_RELAXED,                  \
                                            __HIP_MEMORY_SCOPE_AGENT);                  \
      if (old == bt * 256u - 1u) {                                                      \
        __hip_atomic_store(flag, bt, __ATOMIC_RELAXED, __HIP_MEMORY_SCOPE_AGENT);       \
      } else {                                                                          \
        while (__hip_atomic_load(flag, __ATOMIC_RELAXED, __HIP_MEMORY_SCOPE_AGENT)      \
               < bt) { __builtin_amdgcn_s_sleep(4); }                                   \
      }                                                                                 \
    }                                                                                   \
    __syncthreads();                                                                    \
  } while (0)

  // step-invariant phase-A lane constants (We fragment)
  float wer[16];
#pragma unroll
  for (int j = 0; j < 16; j += 4) {
    float4 w4 = *(const float4*)(&We[ln * 16 + j]);
    wer[j] = w4.x; wer[j + 1] = w4.y; wer[j + 2] = w4.z; wer[j + 3] = w4.w;
  }
  // Phase A geometry: block -> (batch ab, 64-row t-strip); wave -> 4 t-rows
  const int ab = bid >> 3, tbase = (bid & 7) * 64;
  const u16* kb = key + (((long)(ab * TE + tbase)) << 10) + ln * 16;

  for (int s = 0; s < SD; ++s) {
    const int p = s & 1;

    // =================== Phase A: raw scores (+ fc(s-1) on blocks 0-31) ===================
    {
      float qr[16];
      const float* qp = st + QO + ab * 1024 + ln * 16;
      float4 q0, q1, q2, q3;
      ld_dev4x4(qp, qp + 4, qp + 8, qp + 12, q0, q1, q2, q3);
      qr[0] = q0.x; qr[1] = q0.y; qr[2]  = q0.z; qr[3]  = q0.w;
      qr[4] = q1.x; qr[5] = q1.y; qr[6]  = q1.z; qr[7]  = q1.w;
      qr[8] = q2.x; qr[9] = q2.y; qr[10] = q2.z; qr[11] = q2.w;
      qr[12] = q3.x; qr[13] = q3.y; qr[14] = q3.z; qr[15] = q3.w;

      const u16* krow = kb + ((long)(wv * 4) << 10);
      u16x8 a0[4], a1[4];
#pragma unroll
      for (int rr = 0; rr < 4; ++rr) {
        a0[rr] = *(const u16x8*)(krow + ((long)rr << 10));
        a1[rr] = *(const u16x8*)(krow + ((long)rr << 10) + 8);
      }
      float pacc[4] = {0.f, 0.f, 0.f, 0.f};
#pragma unroll
      for (int j = 0; j < 8; ++j) {
#pragma unroll
        for (int rr = 0; rr < 4; ++rr)
          pacc[rr] += tanh_f(qr[j] + b2f(a0[rr][j])) * wer[j];
      }
#pragma unroll
      for (int j = 0; j < 8; ++j) {
#pragma unroll
        for (int rr = 0; rr < 4; ++rr)
          pacc[rr] += tanh_f(qr[8 + j] + b2f(a1[rr][j])) * wer[8 + j];
      }
#pragma unroll
      for (int rr = 0; rr < 4; ++rr)
        for (int off = 32; off; off >>= 1) pacc[rr] += __shfl_down(pacc[rr], off);
      if (ln == 0) {
#pragma unroll
        for (int rr = 0; rr < 4; ++rr)
          st_dev1(st + SCO + ab * 512 + tbase + wv * 4 + rr, pacc[rr]);
      }
    }
    if (bid < 32 && s > 0) {
      // fc for previous step, batch b = bid
      float* h1s = smem;
      const int b = bid;
      if (tid < 512) h1s[tid] = ld_dev1(st + H1O + p * 16384 + b * 512 + tid);
      __syncthreads();
#pragma unroll
      for (int oi = 0; oi < 8; ++oi) {
        const int o = wv * 8 + oi;
        float part = 0.f;
#pragma unroll
        for (int kk = 0; kk < 8; ++kk) {
          int k = kk * 64 + ln;
          part += h1s[k] * fcw[(long)o * 512 + k];
        }
        for (int off = 32; off; off >>= 1) part += __shfl_down(part, off);
        if (ln == 0) {
          float yh = fmaxf(part + fcb[o], 0.f);
          out[((long)b * SD + (s - 1)) * 128 + o] = yh;
          st_dev1(st + YO + b * 128 + o, 1.f + yh);
        }
      }
    }
    GBAR();

    // =================== Phase B: softmax + ctx ===================
    {
      const int b = bid >> 3, dc = bid & 7;
      float* al = smem; float* rr = smem + 512; float* gp = smem + 528;
      if (tid < 512) al[tid] = ld_dev1(st + SCO + b * 512 + tid);
      __syncthreads();
      if (tid < 512) {
        float m = al[tid];
        for (int off = 32; off; off >>= 1) m = fmaxf(m, __shfl_xor(m, off));
        if (ln == 0) rr[wv] = m;
      }
      __syncthreads();
      float M = rr[0];
#pragma unroll
      for (int i = 1; i < 8; ++i) M = fmaxf(M, rr[i]);
      if (tid < 512) {
        float e = __expf(al[tid] - M);
        al[tid] = e;
        for (int off = 32; off; off >>= 1) e += __shfl_xor(e, off);
        if (ln == 0) rr[8 + wv] = e;
      }
      __syncthreads();
      float lsum = rr[8];
#pragma unroll
      for (int i = 9; i < 16; ++i) lsum += rr[i];
      const float inv = __fdividef(1.f, lsum);
      const int tg = tid >> 5, col4 = (tid & 31) * 4;
      float a0 = 0.f, a1 = 0.f, a2 = 0.f, a3 = 0.f;
      const u16* vb = value + (((long)(b * TE)) << 10) + dc * 128 + col4;
#pragma unroll 4
      for (int t = tg; t < 512; t += 32) {
        u16x4 vvv = *(const u16x4*)(vb + ((long)t << 10));
        float av = al[t];
        a0 += av * b2f(vvv[0]); a1 += av * b2f(vvv[1]);
        a2 += av * b2f(vvv[2]); a3 += av * b2f(vvv[3]);
      }
      float4 a4 = {a0, a1, a2, a3};
      *(float4*)(&gp[tg * 132 + col4]) = a4;
      __syncthreads();
      if (tid < 128) {
        float ssum = 0.f;
#pragma unroll
        for (int g = 0; g < 32; ++g) ssum += gp[g * 132 + tid];
        st_dev1(st + CTXO + b * 1024 + dc * 128 + tid, ssum * inv);
      }
    }
    GBAR();

    // =================== Phase C: LSTM0 (block owns 2 h-dims) ===================
    {
      float* xs = smem;            // 32*132 = 4224
      float* wr = smem + 4224;     // 8*132  = 1056
      float* gp = smem + 5280;     // 16*256 = 4096
      const int h0d = bid * 2;
      const int b = tid & 31, jg = tid >> 5, jj = jg * 4;
      float acc[8];
#pragma unroll
      for (int r = 0; r < 8; ++r) acc[r] = 0.f;

      auto csrc = [&](int ch, const float*& src, int& stride, int& col0) {
        if (ch == 0)      { src = st + YO;              stride = 128;  col0 = 0; }
        else if (ch <= 8) { src = st + CTXO;            stride = 1024; col0 = (ch - 1) * 128; }
        else              { src = st + H0O + p * 16384; stride = 512;  col0 = (ch - 9) * 128; }
      };
      auto cwadr = [&](int ch) -> const float* {
        int r = tid >> 5, j = (tid & 31) * 4, g = r >> 1, hh = r & 1;
        return (ch <= 8) ? &wih0[(long)(g * 512 + h0d + hh) * 1152 + ch * 128 + j]
                         : &whh0[(long)(g * 512 + h0d + hh) * 512 + (ch - 9) * 128 + j];
      };

      float4 xreg, wreg;
      {
        const float* sp; int sstr, scol;
        csrc(0, sp, sstr, scol);
        ld4_issue(sp + jg * sstr + scol + (b << 2), xreg);
        if (tid < 256) wreg = *(const float4*)cwadr(0);
      }
      for (int ch = 0; ch < 13; ++ch) {
        vm_wait0();
        __syncthreads();
        *(float4*)(&xs[jg * 132 + (b << 2)]) = xreg;
        if (tid < 256) *(float4*)(&wr[(tid >> 5) * 132 + (tid & 31) * 4]) = wreg;
        __syncthreads();
        if (ch + 1 < 13) {
          const float* sp; int sstr, scol;
          csrc(ch + 1, sp, sstr, scol);
          ld4_issue(sp + jg * sstr + scol + (b << 2), xreg);
          if (tid < 256) wreg = *(const float4*)cwadr(ch + 1);
        }
        const float4 xv = *(const float4*)(&xs[b * 132 + jj]);
#pragma unroll
        for (int r = 0; r < 8; ++r) {
          const float4 w4 = *(const float4*)(&wr[r * 132 + jj]);
          acc[r] += xv.x * w4.x + xv.y * w4.y + xv.z * w4.z + xv.w * w4.w;
        }
      }
#pragma unroll
      for (int r = 0; r < 8; ++r) acc[r] += __shfl_down(acc[r], 32);
      if (ln < 32) {
#pragma unroll
        for (int r = 0; r < 8; ++r) gp[wv * 256 + b * 8 + r] = acc[r];
      }
      __syncthreads();
      if (tid < 256) {
        float v = 0.f;
#pragma unroll
        for (int w = 0; w < 16; ++w) v += gp[w * 256 + tid];
        gp[tid] = v;   // each thread reads only its own column -> no race
      }
      __syncthreads();
      if (tid < 64) {
        const int bb = tid & 31, hh = tid >> 5, h = h0d + hh;
        float gg[4];
#pragma unroll
        for (int g = 0; g < 4; ++g)
          gg[g] = gp[bb * 8 + g * 2 + hh] + bih0[g * 512 + h] + bhh0[g * 512 + h];
        float ig = sigm(gg[0]), fg = sigm(gg[1]), gt = tanh_f(gg[2]), og = sigm(gg[3]);
        int si = bb * 512 + h;
        float c  = ld_dev1(st + C0O + p * 16384 + si);
        float cn = fg * c + ig * gt;
        float hn = og * tanh_f(cn);
        st_dev1(st + H0O + (p ^ 1) * 16384 + si, hn);
        st_dev1(st + C0O + (p ^ 1) * 16384 + si, cn);
      }
    }
    GBAR();

    // =================== Phase D: LSTM1 + q_next (block owns 2 h-dims + 4 q-cols) ===================
    {
      float* xs = smem;            // 4224
      float* wr = smem + 4224;     // 12*132 = 1584
      float* gp = smem + 5808;     // 16*512 = 8192
      const int h0d = bid * 2;
      const int b = tid & 31, jg = tid >> 5, jj = jg * 4;
      float acc[12];
#pragma unroll
      for (int r = 0; r < 12; ++r) acc[r] = 0.f;

      auto dsrc = [&](int ch) -> const float* {
        return (ch < 4) ? (st + H0O + (p ^ 1) * 16384) : (st + H1O + p * 16384);
      };
      auto dwadr = [&](int ch) -> const float* {
        int r = tid >> 5, j = (tid & 31) * 4;
        if (r < 8) {
          int g = r >> 1, hh = r & 1;
          const float* w = (ch < 4) ? wih1 : whh1;
          return &w[(long)(g * 512 + h0d + hh) * 512 + (ch & 3) * 128 + j];
        } else {
          return &Wq[(long)(4 * bid + (r - 8)) * 512 + (ch & 3) * 128 + j];
        }
      };

      float4 xreg, wreg;
      ld4_issue(dsrc(0) + jg * 512 + (b << 2), xreg);
      if (tid < 384) wreg = *(const float4*)dwadr(0);
      for (int ch = 0; ch < 8; ++ch) {
        vm_wait0();
        __syncthreads();
        *(float4*)(&xs[jg * 132 + (b << 2)]) = xreg;
        if (tid < 384) *(float4*)(&wr[(tid >> 5) * 132 + (tid & 31) * 4]) = wreg;
        __syncthreads();
        if (ch + 1 < 8) {
          ld4_issue(dsrc(ch + 1) + jg * 512 + ((ch + 1) & 3) * 128 + (b << 2), xreg);
          if (tid < 384) wreg = *(const float4*)dwadr(ch + 1);
        }
        const float4 xv = *(const float4*)(&xs[b * 132 + jj]);
#pragma unroll
        for (int r = 0; r < 8; ++r) {
          const float4 w4 = *(const float4*)(&wr[r * 132 + jj]);
          acc[r] += xv.x * w4.x + xv.y * w4.y + xv.z * w4.z + xv.w * w4.w;
        }
        if (ch < 4) {
#pragma unroll
          for (int r = 8; r < 12; ++r) {
            const float4 w4 = *(const float4*)(&wr[r * 132 + jj]);
            acc[r] += xv.x * w4.x + xv.y * w4.y + xv.z * w4.z + xv.w * w4.w;
          }
        }
      }
#pragma unroll
      for (int r = 0; r < 12; ++r) acc[r] += __shfl_down(acc[r], 32);
      if (ln < 32) {
#pragma unroll
        for (int r = 0; r < 12; ++r) gp[wv * 512 + b * 16 + r] = acc[r];
      }
      __syncthreads();
      if (tid < 512) {
        const int r = tid & 15;
        if (r < 12) {
          float v = 0.f;
#pragma unroll
          for (int w = 0; w < 16; ++w) v += gp[w * 512 + tid];
          if (r < 8) {
            gp[tid] = v;
          } else {
            const int bb = tid >> 4;
            st_dev1(st + QO + bb * 1024 + 4 * bid + (r - 8), v);
          }
        }
      }
      __syncthreads();
      if (tid < 64) {
        const int bb = tid & 31, hh = tid >> 5, h = h0d + hh;
        float gg[4];
#pragma unroll
        for (int g = 0; g < 4; ++g)
          gg[g] = gp[bb * 16 + g * 2 + hh] + bih1[g * 512 + h] + bhh1[g * 512 + h];
        float ig = sigm(gg[0]), fg = sigm(gg[1]), gt = tanh_f(gg[2]), og = sigm(gg[3]);
        int si = bb * 512 + h;
        float c  = ld_dev1(st + C1O + p * 16384 + si);
        float cn = fg * c + ig * gt;
        float hn = og * tanh_f(cn);
        st_dev1(st + H1O + (p ^ 1) * 16384 + si, hn);
        st_dev1(st + C1O + (p ^ 1) * 16384 + si, cn);
      }
    }
    GBAR();
  }

  // =================== Tail: fc for step SD-1 (h1 at parity 0) ===================
  if (bid < 128) {
    float* h1s = smem;
    const int b = bid >> 2, og = (bid & 3) * 32;
    if (tid < 512) h1s[tid] = ld_dev1(st + H1O + b * 512 + tid);
    __syncthreads();
#pragma unroll
    for (int oi = 0; oi < 2; ++oi) {
      const int o = og + wv * 2 + oi;
      float part = 0.f;
#pragma unroll
      for (int kk = 0; kk < 8; ++kk) {
        int k = kk * 64 + ln;
        part += h1s[k] * fcw[(long)o * 512 + k];
      }
      for (int off = 32; off; off >>= 1) part += __shfl_down(part, off);
      if (ln == 0) {
        float yh = fmaxf(part + fcb[o], 0.f);
        out[((long)b * SD + (SD - 1)) * 128 + o] = yh;
      }
    }
  }
#undef GBAR
}

extern "C" void kernel_launch(void* const* d_in, const int* in_sizes, int n_in,
                              void* d_out, int out_size, void* d_ws, size_t ws_size,
                              hipStream_t stream) {
  (void)in_sizes; (void)n_in; (void)out_size; (void)ws_size;
  float* out = (float*)d_out;

  const float* E    = (const float*)d_in[0];
  const float* h0   = (const float*)d_in[1];
  const float* c0   = (const float*)d_in[2];
  const float* Wk   = (const float*)d_in[3];
  const float* Wq   = (const float*)d_in[4];
  const float* Wv   = (const float*)d_in[5];
  const float* We   = (const float*)d_in[6];
  const float* wih0 = (const float*)d_in[7];
  const float* whh0 = (const float*)d_in[8];
  const float* bih0 = (const float*)d_in[9];
  const float* bhh0 = (const float*)d_in[10];
  const float* wih1 = (const float*)d_in[11];
  const float* whh1 = (const float*)d_in[12];
  const float* bih1 = (const float*)d_in[13];
  const float* bhh1 = (const float*)d_in[14];
  const float* fcw  = (const float*)d_in[15];
  const float* fcb  = (const float*)d_in[16];

  // ws layout: key bf16 33.5MB | value bf16 33.5MB | st ~1MB
  u16* key   = (u16*)d_ws;
  u16* value = key + 16777216;
  float* st  = (float*)d_ws + 16777216;   // byte 67,108,864

  gemm_kv<<<dim3(256, 16, 2), 256, 0, stream>>>(E, Wk, Wv, key, value);
  init_state<<<64, 256, 0, stream>>>(h0, c0, st);
  qproj<<<128, 256, 0, stream>>>(h0, Wq, st);

  decode_loop<<<256, 1024, 0, stream>>>(key, value, We,
                                        wih0, whh0, bih0, bhh0,
                                        wih1, whh1, bih1, bhh1,
                                        Wq, fcw, fcb, st, out);
}

// Round 5
// 14684.723 us; speedup vs baseline: 1.9984x; 1.9984x over previous
//
#include <hip/hip_runtime.h>
#include <cstdint>

// Problem dims
#define TE    512
#define SD    128

typedef unsigned short u16;
typedef u16 u16x4 __attribute__((ext_vector_type(4)));
typedef u16 u16x8 __attribute__((ext_vector_type(8)));

// State region offsets (floats), relative to st pointer (st = d_ws + 67,108,864 B)
#define QO    0          // [32][1024]
#define SCO   32768      // [32][512]
#define SUBO  49152      // 8 sub-barrier counters, 64B apart (128 floats)
#define MBO   49280      // master counter
#define FLG2  49312      // release flag (separate line)
#define CTXO  81920      // [32][1024]
#define YO    114688     // [32][128]
#define H0O   118784     // [2][32][512]
#define C0O   151552
#define H1O   184320
#define C1O   217088

__device__ __forceinline__ float b2f(u16 v) { return __uint_as_float(((unsigned)v) << 16); }
__device__ __forceinline__ u16 f2b(float f) {
  unsigned u = __float_as_uint(f);
  return (u16)((u + 0x7FFFu + ((u >> 16) & 1u)) >> 16);
}
__device__ __forceinline__ float tanh_f(float x) {
  float xc = fminf(12.f, fmaxf(-12.f, x));
  float e  = __expf(2.f * xc);
  return __fdividef(e - 1.f, e + 1.f);
}
__device__ __forceinline__ float sigm(float x) {
  float xc = fminf(30.f, fmaxf(-30.f, x));
  return __fdividef(1.f, 1.f + __expf(-xc));
}

// ---- device-coherent (sc1) accessors: bypass non-coherent per-XCD L2 ----
__device__ __forceinline__ float ld_dev1(const float* p) {
  float r;
  asm volatile("global_load_dword %0, %1, off sc1\n\ts_waitcnt vmcnt(0)"
               : "=&v"(r) : "v"(p) : "memory");
  return r;
}
__device__ __forceinline__ void st_dev1(float* p, float v) {
  asm volatile("global_store_dword %0, %1, off sc1" :: "v"(p), "v"(v) : "memory");
}
// issue-only loads (no wait); pair with vm_wait0()
__device__ __forceinline__ void ld1_issue(const float* p, float& r) {
  asm volatile("global_load_dword %0, %1, off sc1" : "=&v"(r) : "v"(p));
}
__device__ __forceinline__ void ld2_issue(const float* p, float2& r) {
  asm volatile("global_load_dwordx2 %0, %1, off sc1" : "=&v"(r) : "v"(p));
}
__device__ __forceinline__ void vm_wait0() { asm volatile("s_waitcnt vmcnt(0)" ::: "memory"); }

__device__ __forceinline__ unsigned atom_inc_dev(unsigned* p) {
  return __hip_atomic_fetch_add(p, 1u, __ATOMIC_RELAXED, __HIP_MEMORY_SCOPE_AGENT);
}
__device__ __forceinline__ unsigned atom_ld_dev(unsigned* p) {
  return __hip_atomic_load(p, __ATOMIC_RELAXED, __HIP_MEMORY_SCOPE_AGENT);
}
__device__ __forceinline__ void atom_st_dev(unsigned* p, unsigned v) {
  __hip_atomic_store(p, v, __ATOMIC_RELAXED, __HIP_MEMORY_SCOPE_AGENT);
}

// ---------------- NT GEMM: key=E@Wk^T, value=E@Wv^T (fp32 in, bf16 out) ----------------
__global__ __launch_bounds__(256)
void gemm_kv(const float* __restrict__ E, const float* __restrict__ Wk,
             const float* __restrict__ Wv, u16* __restrict__ key, u16* __restrict__ value) {
  const float* B = blockIdx.z ? Wv : Wk;
  u16* outp = blockIdx.z ? value : key;
  __shared__ float Asm[16][68], Bsm[16][68];
  const int tid = threadIdx.x;
  const int tm = blockIdx.x * 64, tn = blockIdx.y * 64;
  const int lr = tid >> 2, lc = (tid & 3) * 4;
  const int tx = tid & 15, ty = tid >> 4;
  float acc[4][4] = {};
  for (int k0 = 0; k0 < 1024; k0 += 16) {
    float4 av = *(const float4*)(&E[(long)(tm + lr) * 1024 + k0 + lc]);
    float4 bv = *(const float4*)(&B[(long)(tn + lr) * 1024 + k0 + lc]);
    Asm[lc][lr] = av.x; Asm[lc + 1][lr] = av.y; Asm[lc + 2][lr] = av.z; Asm[lc + 3][lr] = av.w;
    Bsm[lc][lr] = bv.x; Bsm[lc + 1][lr] = bv.y; Bsm[lc + 2][lr] = bv.z; Bsm[lc + 3][lr] = bv.w;
    __syncthreads();
#pragma unroll
    for (int kk = 0; kk < 16; ++kk) {
      float4 a4 = *(const float4*)(&Asm[kk][ty * 4]);
      float4 b4 = *(const float4*)(&Bsm[kk][tx * 4]);
      acc[0][0] += a4.x * b4.x; acc[0][1] += a4.x * b4.y; acc[0][2] += a4.x * b4.z; acc[0][3] += a4.x * b4.w;
      acc[1][0] += a4.y * b4.x; acc[1][1] += a4.y * b4.y; acc[1][2] += a4.y * b4.z; acc[1][3] += a4.y * b4.w;
      acc[2][0] += a4.z * b4.x; acc[2][1] += a4.z * b4.y; acc[2][2] += a4.z * b4.z; acc[2][3] += a4.z * b4.w;
      acc[3][0] += a4.w * b4.x; acc[3][1] += a4.w * b4.y; acc[3][2] += a4.w * b4.z; acc[3][3] += a4.w * b4.w;
    }
    __syncthreads();
  }
#pragma unroll
  for (int i = 0; i < 4; ++i)
#pragma unroll
    for (int j = 0; j < 4; ++j)
      outp[(long)(tm + ty * 4 + i) * 1024 + tn + tx * 4 + j] = f2b(acc[i][j]);
}

// ---------------- init: h/c -> parity-0 state, zero y, zero barrier region ----------------
__global__ __launch_bounds__(256)
void init_state(const float* __restrict__ h0, const float* __restrict__ c0, float* __restrict__ st) {
  int i = blockIdx.x * 256 + threadIdx.x;   // 16384 threads
  st[H0O + i] = h0[i];
  st[H1O + i] = h0[16384 + i];
  st[C0O + i] = c0[i];
  st[C1O + i] = c0[16384 + i];
  if (i < 4096) st[YO + i] = 0.f;
  if (i < 256) *(unsigned*)(st + SUBO + i) = 0u;
}

// ---------------- q0 = h0_layer0 @ Wq^T ----------------
__global__ __launch_bounds__(256)
void qproj(const float* __restrict__ h0, const float* __restrict__ Wq, float* __restrict__ st) {
  __shared__ float hr[512];
  const int b = blockIdx.x >> 2, o = (blockIdx.x & 3) * 256 + threadIdx.x;
  for (int i = threadIdx.x; i < 512; i += 256) hr[i] = h0[b * 512 + i];
  __syncthreads();
  float acc = 0.f;
  for (int k = 0; k < 512; k += 4) {
    float4 wv = *(const float4*)(&Wq[(long)o * 512 + k]);
    acc += hr[k] * wv.x + hr[k + 1] * wv.y + hr[k + 2] * wv.z + hr[k + 3] * wv.w;
  }
  st[QO + b * 1024 + o] = acc;
}

// ---------------- fused decode loop: 256 blocks x 512 threads ----------------
// 2 waves/SIMD; sc1 state transport; hierarchical barrier (8x32 + 8, flag release).
// A: scores (ab=bid>>3, 64-t strip) + fc(s-1) on blocks 0-31
// B: softmax+ctx (b=bid>>3, dc=bid&7)
// C: LSTM0  block = (hg=bid>>2: 8 h-dims, bg=bid&3: 8 batches)
// D: LSTM1+q block = same split; 32 gate rows + 16 q rows
__global__ __launch_bounds__(512, 2)
void decode_loop(const u16* __restrict__ key, const u16* __restrict__ value,
                 const float* __restrict__ We,
                 const float* __restrict__ wih0, const float* __restrict__ whh0,
                 const float* __restrict__ bih0, const float* __restrict__ bhh0,
                 const float* __restrict__ wih1, const float* __restrict__ whh1,
                 const float* __restrict__ bih1, const float* __restrict__ bhh1,
                 const float* __restrict__ Wq,
                 const float* __restrict__ fcw, const float* __restrict__ fcb,
                 float* st, float* out) {
  __shared__ float smem[7776];   // max phase D: xs 1056 + wr 6336 + gp 384
  const int tid = threadIdx.x, wv = tid >> 6, ln = tid & 63;
  const int bid = blockIdx.x;
  unsigned* subc = (unsigned*)(st + SUBO) + (bid & 7) * 16;
  unsigned* mast = (unsigned*)(st + MBO);
  unsigned* flag = (unsigned*)(st + FLG2);
  unsigned bt = 0;

#define GBAR() do {                                                                     \
    ++bt;                                                                               \
    asm volatile("s_waitcnt vmcnt(0)" ::: "memory");                                    \
    __syncthreads();                                                                    \
    if (tid == 0) {                                                                     \
      unsigned old = atom_inc_dev(subc);                                                \
      if (old == bt * 32u - 1u) {                                                       \
        unsigned mo = atom_inc_dev(mast);                                               \
        if (mo == bt * 8u - 1u) atom_st_dev(flag, bt);                                  \
        else while (atom_ld_dev(flag) < bt) __builtin_amdgcn_s_sleep(2);                \
      } else {                                                                          \
        while (atom_ld_dev(flag) < bt) __builtin_amdgcn_s_sleep(2);                     \
      }                                                                                 \
    }                                                                                   \
    __syncthreads();                                                                    \
  } while (0)

  // step-invariant phase-A lane constants (We fragment)
  float wer[16];
#pragma unroll
  for (int j = 0; j < 16; j += 4) {
    float4 w4 = *(const float4*)(&We[ln * 16 + j]);
    wer[j] = w4.x; wer[j + 1] = w4.y; wer[j + 2] = w4.z; wer[j + 3] = w4.w;
  }
  const int ab = bid >> 3, tstrip = (bid & 7) * 64;
  const u16* kbase = key + (((long)(ab * TE + tstrip)) << 10) + ln * 16;
  const int hg = bid >> 2, bg = bid & 3;

  for (int s = 0; s < SD; ++s) {
    const int p = s & 1;

    // =================== Phase A: scores + fc(s-1) on blocks 0-31 ===================
    {
      float* qs  = smem;          // 1024
      float* h1s = smem + 1024;   // 512
      const bool dofc = (bid < 32) && (s > 0);
      float2 qv; float h1v;
      ld2_issue(st + QO + ab * 1024 + tid * 2, qv);
      if (dofc) ld1_issue(st + H1O + p * 16384 + bid * 512 + tid, h1v);
      vm_wait0();
      qs[tid * 2] = qv.x; qs[tid * 2 + 1] = qv.y;
      if (dofc) h1s[tid] = h1v;
      __syncthreads();
      float qr[16];
#pragma unroll
      for (int j = 0; j < 16; ++j) qr[j] = qs[ln * 16 + j];
#pragma unroll
      for (int rnd = 0; rnd < 2; ++rnd) {
        const u16* krow = kbase + ((long)(wv * 8 + rnd * 4) << 10);
        u16x8 a0[4], a1[4];
#pragma unroll
        for (int r = 0; r < 4; ++r) {
          a0[r] = *(const u16x8*)(krow + ((long)r << 10));
          a1[r] = *(const u16x8*)(krow + ((long)r << 10) + 8);
        }
        float pacc[4] = {0.f, 0.f, 0.f, 0.f};
#pragma unroll
        for (int j = 0; j < 8; ++j) {
#pragma unroll
          for (int r = 0; r < 4; ++r)
            pacc[r] += tanh_f(qr[j] + b2f(a0[r][j])) * wer[j];
        }
#pragma unroll
        for (int j = 0; j < 8; ++j) {
#pragma unroll
          for (int r = 0; r < 4; ++r)
            pacc[r] += tanh_f(qr[8 + j] + b2f(a1[r][j])) * wer[8 + j];
        }
#pragma unroll
        for (int r = 0; r < 4; ++r)
          for (int off = 32; off; off >>= 1) pacc[r] += __shfl_down(pacc[r], off);
        if (ln == 0) {
#pragma unroll
          for (int r = 0; r < 4; ++r)
            st_dev1(st + SCO + ab * 512 + tstrip + wv * 8 + rnd * 4 + r, pacc[r]);
        }
      }
      if (dofc) {
#pragma unroll
        for (int oi = 0; oi < 16; ++oi) {
          const int o = wv * 16 + oi;
          float part = 0.f;
#pragma unroll
          for (int kk = 0; kk < 8; ++kk) {
            int k = kk * 64 + ln;
            part += h1s[k] * fcw[(long)o * 512 + k];
          }
          for (int off = 32; off; off >>= 1) part += __shfl_down(part, off);
          if (ln == 0) {
            float yh = fmaxf(part + fcb[o], 0.f);
            out[((long)bid * SD + (s - 1)) * 128 + o] = yh;
            st_dev1(st + YO + bid * 128 + o, 1.f + yh);
          }
        }
      }
    }
    GBAR();

    // =================== Phase B: softmax + ctx ===================
    {
      const int b = bid >> 3, dc = bid & 7;
      float* al = smem; float* rr = smem + 512; float* gp = smem + 528;  // gp 16*132
      al[tid] = ld_dev1(st + SCO + b * 512 + tid);
      __syncthreads();
      float m = al[tid];
      for (int off = 32; off; off >>= 1) m = fmaxf(m, __shfl_xor(m, off));
      if (ln == 0) rr[wv] = m;
      __syncthreads();
      float M = rr[0];
#pragma unroll
      for (int i = 1; i < 8; ++i) M = fmaxf(M, rr[i]);
      float e = __expf(al[tid] - M);
      al[tid] = e;
      for (int off = 32; off; off >>= 1) e += __shfl_xor(e, off);
      if (ln == 0) rr[8 + wv] = e;
      __syncthreads();
      float lsum = rr[8];
#pragma unroll
      for (int i = 9; i < 16; ++i) lsum += rr[i];
      const float inv = __fdividef(1.f, lsum);
      const int tg = tid >> 5, col4 = (tid & 31) * 4;
      float a0 = 0.f, a1 = 0.f, a2 = 0.f, a3 = 0.f;
      const u16* vb = value + (((long)(b * TE)) << 10) + dc * 128 + col4;
#pragma unroll 4
      for (int t = tg; t < 512; t += 16) {
        u16x4 vvv = *(const u16x4*)(vb + ((long)t << 10));
        float av = al[t];
        a0 += av * b2f(vvv[0]); a1 += av * b2f(vvv[1]);
        a2 += av * b2f(vvv[2]); a3 += av * b2f(vvv[3]);
      }
      float4 a4 = {a0, a1, a2, a3};
      *(float4*)(&gp[tg * 132 + col4]) = a4;
      __syncthreads();
      if (tid < 128) {
        float ssum = 0.f;
#pragma unroll
        for (int g = 0; g < 16; ++g) ssum += gp[g * 132 + tid];
        st_dev1(st + CTXO + b * 1024 + dc * 128 + tid, ssum * inv);
      }
    }
    GBAR();

    // =================== Phase C: LSTM0 — block = 8 h-dims x 8 batches ===================
    {
      float* xs = smem;            // 8*132  = 1056
      float* wr = smem + 1056;     // 32*132 = 4224
      float* gp = smem + 5280;     // 256
      const int bs = tid >> 6, j2 = (tid & 63) * 2;          // xs stage
      const int wrow = tid >> 4, wj = (tid & 15) * 8;        // wr stage (2 float4)
      const int wg = wrow >> 3, whh = wrow & 7;
      const int cr = ln & 31, jh = ln >> 5, jbase = jh * 64; // compute
      float acc = 0.f;
      float2 xn; float4 wn0, wn1;

      {
        const float* xp = st + YO + (bg * 8 + bs) * 128 + j2;
        ld2_issue(xp, xn);
        const float* wp = &wih0[(long)(wg * 512 + hg * 8 + whh) * 1152 + 0 * 128 + wj];
        wn0 = *(const float4*)wp; wn1 = *(const float4*)(wp + 4);
      }
      for (int ch = 0; ch < 13; ++ch) {
        vm_wait0();
        __syncthreads();
        *(float2*)(&xs[bs * 132 + j2]) = xn;
        *(float4*)(&wr[wrow * 132 + wj]) = wn0;
        *(float4*)(&wr[wrow * 132 + wj + 4]) = wn1;
        __syncthreads();
        if (ch + 1 < 13) {
          const int cn = ch + 1;
          const float* xp;
          if (cn <= 8) xp = st + CTXO + (bg * 8 + bs) * 1024 + (cn - 1) * 128 + j2;
          else         xp = st + H0O + p * 16384 + (bg * 8 + bs) * 512 + (cn - 9) * 128 + j2;
          ld2_issue(xp, xn);
          const float* wp = (cn <= 8)
            ? &wih0[(long)(wg * 512 + hg * 8 + whh) * 1152 + cn * 128 + wj]
            : &whh0[(long)(wg * 512 + hg * 8 + whh) * 512 + (cn - 9) * 128 + wj];
          wn0 = *(const float4*)wp; wn1 = *(const float4*)(wp + 4);
        }
#pragma unroll
        for (int k = 0; k < 16; ++k) {
          const float4 xv = *(const float4*)(&xs[wv * 132 + jbase + k * 4]);
          const float4 w4 = *(const float4*)(&wr[cr * 132 + jbase + k * 4]);
          acc += xv.x * w4.x + xv.y * w4.y + xv.z * w4.z + xv.w * w4.w;
        }
      }
      acc += __shfl_down(acc, 32);
      if (ln < 32) gp[wv * 32 + cr] = acc;
      __syncthreads();
      if (tid < 64) {
        const int bl = tid >> 3, hh = tid & 7;
        const int batch = bg * 8 + bl, h = hg * 8 + hh;
        float gg[4];
#pragma unroll
        for (int g = 0; g < 4; ++g)
          gg[g] = gp[bl * 32 + g * 8 + hh] + bih0[g * 512 + h] + bhh0[g * 512 + h];
        float ig = sigm(gg[0]), fg = sigm(gg[1]), gt = tanh_f(gg[2]), og = sigm(gg[3]);
        int si = batch * 512 + h;
        float c  = ld_dev1(st + C0O + p * 16384 + si);
        float cn = fg * c + ig * gt;
        float hn = og * tanh_f(cn);
        st_dev1(st + H0O + (p ^ 1) * 16384 + si, hn);
        st_dev1(st + C0O + (p ^ 1) * 16384 + si, cn);
      }
    }
    GBAR();

    // =================== Phase D: LSTM1 + q — block = 8 h-dims x 8 batches + 16 q cols ===================
    {
      float* xs = smem;            // 1056
      float* wr = smem + 1056;     // 48*132 = 6336
      float* gp = smem + 7392;     // 384
      const int bs = tid >> 6, j2 = (tid & 63) * 2;
      const int wj4 = (tid & 31) * 4, wr0 = tid >> 5;        // 3 rounds: row = wr0 + rnd*16
      float acc = 0.f;
      float2 xn; float4 wn[3];

      auto wadrD = [&](int ch, int rnd) -> const float* {
        int r = wr0 + rnd * 16;
        if (r < 32) {
          int g = r >> 3, hh = r & 7;
          const float* w = (ch < 4) ? wih1 : whh1;
          return &w[(long)(g * 512 + hg * 8 + hh) * 512 + (ch & 3) * 128 + wj4];
        }
        return &Wq[(long)(hg * 16 + (r - 32)) * 512 + (ch & 3) * 128 + wj4];
      };

      {
        const float* xp = st + H0O + (p ^ 1) * 16384 + (bg * 8 + bs) * 512 + j2;
        ld2_issue(xp, xn);
#pragma unroll
        for (int rnd = 0; rnd < 3; ++rnd) wn[rnd] = *(const float4*)wadrD(0, rnd);
      }
      for (int ch = 0; ch < 8; ++ch) {
        vm_wait0();
        __syncthreads();
        *(float2*)(&xs[bs * 132 + j2]) = xn;
#pragma unroll
        for (int rnd = 0; rnd < 3; ++rnd) {
          int r = wr0 + rnd * 16;
          if (r < 32 || ch < 4) *(float4*)(&wr[r * 132 + wj4]) = wn[rnd];
        }
        __syncthreads();
        if (ch + 1 < 8) {
          const int cn = ch + 1;
          const float* xp = (cn < 4)
            ? st + H0O + (p ^ 1) * 16384 + (bg * 8 + bs) * 512 + cn * 128 + j2
            : st + H1O + p * 16384 + (bg * 8 + bs) * 512 + (cn & 3) * 128 + j2;
          ld2_issue(xp, xn);
#pragma unroll
          for (int rnd = 0; rnd < 3; ++rnd)
            if (wr0 + rnd * 16 < 32 || cn < 4) wn[rnd] = *(const float4*)wadrD(cn, rnd);
        }
        if (ln < 48 && (ln < 32 || ch < 4)) {
#pragma unroll
          for (int k = 0; k < 32; ++k) {
            const float4 xv = *(const float4*)(&xs[wv * 132 + k * 4]);
            const float4 w4 = *(const float4*)(&wr[ln * 132 + k * 4]);
            acc += xv.x * w4.x + xv.y * w4.y + xv.z * w4.z + xv.w * w4.w;
          }
        }
      }
      if (ln < 32) gp[wv * 48 + ln] = acc;
      else if (ln < 48)
        st_dev1(st + QO + (bg * 8 + wv) * 1024 + hg * 16 + (ln - 32), acc);
      __syncthreads();
      if (tid < 64) {
        const int bl = tid >> 3, hh = tid & 7;
        const int batch = bg * 8 + bl, h = hg * 8 + hh;
        float gg[4];
#pragma unroll
        for (int g = 0; g < 4; ++g)
          gg[g] = gp[bl * 48 + g * 8 + hh] + bih1[g * 512 + h] + bhh1[g * 512 + h];
        float ig = sigm(gg[0]), fg = sigm(gg[1]), gt = tanh_f(gg[2]), og = sigm(gg[3]);
        int si = batch * 512 + h;
        float c  = ld_dev1(st + C1O + p * 16384 + si);
        float cn = fg * c + ig * gt;
        float hn = og * tanh_f(cn);
        st_dev1(st + H1O + (p ^ 1) * 16384 + si, hn);
        st_dev1(st + C1O + (p ^ 1) * 16384 + si, cn);
      }
    }
    GBAR();
  }

  // =================== Tail: fc for step SD-1 (h1 at parity 0) ===================
  if (bid < 128) {
    float* h1s = smem;
    const int b = bid >> 2, og = (bid & 3) * 32;
    h1s[tid] = ld_dev1(st + H1O + b * 512 + tid);
    __syncthreads();
#pragma unroll
    for (int oi = 0; oi < 4; ++oi) {
      const int o = og + wv * 4 + oi;
      float part = 0.f;
#pragma unroll
      for (int kk = 0; kk < 8; ++kk) {
        int k = kk * 64 + ln;
        part += h1s[k] * fcw[(long)o * 512 + k];
      }
      for (int off = 32; off; off >>= 1) part += __shfl_down(part, off);
      if (ln == 0) {
        float yh = fmaxf(part + fcb[o], 0.f);
        out[((long)b * SD + (SD - 1)) * 128 + o] = yh;
      }
    }
  }
#undef GBAR
}

extern "C" void kernel_launch(void* const* d_in, const int* in_sizes, int n_in,
                              void* d_out, int out_size, void* d_ws, size_t ws_size,
                              hipStream_t stream) {
  (void)in_sizes; (void)n_in; (void)out_size; (void)ws_size;
  float* out = (float*)d_out;

  const float* E    = (const float*)d_in[0];
  const float* h0   = (const float*)d_in[1];
  const float* c0   = (const float*)d_in[2];
  const float* Wk   = (const float*)d_in[3];
  const float* Wq   = (const float*)d_in[4];
  const float* Wv   = (const float*)d_in[5];
  const float* We   = (const float*)d_in[6];
  const float* wih0 = (const float*)d_in[7];
  const float* whh0 = (const float*)d_in[8];
  const float* bih0 = (const float*)d_in[9];
  const float* bhh0 = (const float*)d_in[10];
  const float* wih1 = (const float*)d_in[11];
  const float* whh1 = (const float*)d_in[12];
  const float* bih1 = (const float*)d_in[13];
  const float* bhh1 = (const float*)d_in[14];
  const float* fcw  = (const float*)d_in[15];
  const float* fcb  = (const float*)d_in[16];

  // ws layout: key bf16 33.5MB | value bf16 33.5MB | st ~1MB
  u16* key   = (u16*)d_ws;
  u16* value = key + 16777216;
  float* st  = (float*)d_ws + 16777216;   // byte 67,108,864

  gemm_kv<<<dim3(256, 16, 2), 256, 0, stream>>>(E, Wk, Wv, key, value);
  init_state<<<64, 256, 0, stream>>>(h0, c0, st);
  qproj<<<128, 256, 0, stream>>>(h0, Wq, st);

  decode_loop<<<256, 512, 0, stream>>>(key, value, We,
                                       wih0, whh0, bih0, bhh0,
                                       wih1, whh1, bih1, bhh1,
                                       Wq, fcw, fcb, st, out);
}